// Round 1
// baseline (583.289 us; speedup 1.0000x reference)
//
#include <hip/hip_runtime.h>
#include <math.h>

#define NCH 192
#define NB 8
#define SPAT 32768           // 32^3
#define TILE_M 64
#define TILES_PER_B (SPAT / TILE_M)   // 512
#define NWG (NB * TILES_PER_B)        // 4096
#define NELEM_PER_B ((size_t)NCH * SPAT)  // 6291456

typedef short s16x8 __attribute__((ext_vector_type(8)));
typedef float f32x4 __attribute__((ext_vector_type(4)));

__device__ __forceinline__ float bf2f(unsigned short h) {
  return __uint_as_float(((unsigned)h) << 16);
}
__device__ __forceinline__ unsigned short f2bf(float f) {
  unsigned u = __float_as_uint(f);
  u += 0x7FFF + ((u >> 16) & 1);   // round-to-nearest-even
  return (unsigned short)(u >> 16);
}

// erf via Abramowitz-Stegun 7.1.26, |abs err| < 1.5e-7 (plenty vs 9e-2 budget)
__device__ __forceinline__ float erf_fast(float x) {
  float ax = fabsf(x);
  float t = 1.0f / fmaf(0.3275911f, ax, 1.0f);
  float p = t * fmaf(t, fmaf(t, fmaf(t, fmaf(t, 1.061405429f, -1.453152027f),
                                     1.421413741f), -0.284496736f), 0.254829592f);
  float r = 1.0f - p * __expf(-ax * ax);
  return copysignf(r, x);
}
__device__ __forceinline__ float gelu_exact(float x) {
  return 0.5f * x * (1.0f + erf_fast(x * 0.70710678118654752f));
}

// reflect-shift source position: out[i] = x[i-s], reflect(-1)->1, reflect(32)->30
template <int AX>  // 0 none, 2=D, 3=H, 4=W
__device__ __forceinline__ int shift_src(int p, int s) {
  if (AX == 0) return p;
  const int SH = (AX == 4) ? 0 : (AX == 3) ? 5 : 10;
  int i = (p >> SH) & 31;
  int j = i - s;
  j = (j < 0) ? 1 : j;
  j = (j > 31) ? 30 : j;
  return p + ((j - i) << SH);
}

// ---------------------------------------------------------------------------
// Unified GEMM pass: out[b][p][o] (bf16) or out[b][o][p] (f32) = W @ in + bias
//   AX:   shift axis applied to B-fragment source positions
//   EPI:  0 bias only; 1 bias+stats; 2 bias+gelu+stats
//   OUTF: 0 bf16 position-major; 1 f32 channel-major (final output)
//   INF:  0 bf16 position-major; 1 f32 channel-major gather (K1 reads x)
//   PERB: per-sample weight/bias matrices (folded norm2 in K3)
// Wave w computes out-channels [48w,48w+48) x 64 positions: 3x4 MFMA frags.
// ---------------------------------------------------------------------------
template <int AX, int EPI, int OUTF, int INF, int PERB>
__global__ void gemm_pass(const void* __restrict__ inv,
                          const unsigned short* __restrict__ wmat,
                          const float* __restrict__ bias,
                          void* __restrict__ outv,
                          float* __restrict__ partials) {
  int wg = blockIdx.x;
  int b = wg / TILES_PER_B;
  int p0 = (wg % TILES_PER_B) * TILE_M;
  int tid = threadIdx.x;
  int wave = tid >> 6;
  int lane = tid & 63;
  int col = lane & 15;
  int kg = lane >> 4;

  const unsigned short* wbase = wmat + (PERB ? (size_t)b * NCH * NCH : 0);
  const float* bbase = bias + (PERB ? b * NCH : 0);
  const unsigned short* inb = (const unsigned short*)inv;
  const float* xin = (const float*)inv;

  f32x4 acc[3][4] = {};

#pragma unroll
  for (int ks = 0; ks < 6; ++ks) {
    int k0 = ks * 32 + kg * 8;
    // A fragments: weights, row = out-channel, 8 consecutive k (contiguous 16B)
    s16x8 af[3];
#pragma unroll
    for (int r = 0; r < 3; ++r) {
      int row = wave * 48 + r * 16 + col;
      af[r] = *(const s16x8*)(wbase + row * NCH + k0);
    }
    // B fragments: activations, col = position, 8 consecutive input channels
    int s_ = (k0 >> 6) - 1;  // channel-chunk shift: -1, 0, +1
    s16x8 bf[4];
#pragma unroll
    for (int m = 0; m < 4; ++m) {
      int p = p0 + m * 16 + col;
      if (INF == 1) {
        // x is fp32 channel-major: gather 8 dwords at stride SPAT
        const float* xp = xin + (size_t)b * NELEM_PER_B + (size_t)k0 * SPAT + p;
        s16x8 t;
#pragma unroll
        for (int j = 0; j < 8; ++j) t[j] = (short)f2bf(xp[(size_t)j * SPAT]);
        bf[m] = t;
      } else {
        int ps = shift_src<AX>(p, s_);
        bf[m] = *(const s16x8*)(inb + ((size_t)b * SPAT + ps) * NCH + k0);
      }
    }
#pragma unroll
    for (int r = 0; r < 3; ++r)
#pragma unroll
      for (int m = 0; m < 4; ++m)
        acc[r][m] = __builtin_amdgcn_mfma_f32_16x16x32_bf16(af[r], bf[m], acc[r][m], 0, 0, 0);
  }

  // Epilogue: D mapping col=lane&15, row=(lane>>4)*4+j  [m89-verified]
  float ssum = 0.f, ssq = 0.f;
  unsigned short* outb = (unsigned short*)outv;
  float* outf = (float*)outv;
#pragma unroll
  for (int r = 0; r < 3; ++r) {
    int rowb = wave * 48 + r * 16 + kg * 4;
    f32x4 bs = *(const f32x4*)(bbase + rowb);
#pragma unroll
    for (int m = 0; m < 4; ++m) {
      int p = p0 + m * 16 + col;
      float v[4];
#pragma unroll
      for (int j = 0; j < 4; ++j) {
        float t = acc[r][m][j] + bs[j];
        if (EPI == 2) t = gelu_exact(t);
        if (EPI >= 1) { ssum += t; ssq = fmaf(t, t, ssq); }
        v[j] = t;
      }
      if (OUTF == 0) {
        uint2 pk;
        pk.x = (unsigned)f2bf(v[0]) | ((unsigned)f2bf(v[1]) << 16);
        pk.y = (unsigned)f2bf(v[2]) | ((unsigned)f2bf(v[3]) << 16);
        *(uint2*)(outb + ((size_t)b * SPAT + p) * NCH + rowb) = pk;
      } else {
#pragma unroll
        for (int j = 0; j < 4; ++j)
          outf[((size_t)b * NCH + rowb + j) * SPAT + p] = v[j];
      }
    }
  }

  if (EPI >= 1) {
#pragma unroll
    for (int off = 1; off < 64; off <<= 1) {
      ssum += __shfl_xor(ssum, off, 64);
      ssq += __shfl_xor(ssq, off, 64);
    }
    __shared__ float red[4][2];
    if (lane == 0) { red[wave][0] = ssum; red[wave][1] = ssq; }
    __syncthreads();
    if (tid == 0) {
      partials[wg * 2]     = red[0][0] + red[1][0] + red[2][0] + red[3][0];
      partials[wg * 2 + 1] = red[0][1] + red[1][1] + red[2][1] + red[3][1];
    }
  }
}

// Deterministic per-sample stats finalize: partials -> A[c]=rs*nw[c], C[c]=nb[c]-mu*A[c]
__global__ void stats_finalize(const float* __restrict__ partials,
                               const float* __restrict__ nw,
                               const float* __restrict__ nb,
                               float* __restrict__ AC) {
  int b = blockIdx.x;
  int tid = threadIdx.x;
  __shared__ float s0[256], s1[256];
  float a = 0.f, c = 0.f;
  for (int i = tid; i < TILES_PER_B; i += 256) {
    a += partials[(b * TILES_PER_B + i) * 2];
    c += partials[(b * TILES_PER_B + i) * 2 + 1];
  }
  s0[tid] = a; s1[tid] = c;
  __syncthreads();
  for (int st = 128; st > 0; st >>= 1) {
    if (tid < st) { s0[tid] += s0[tid + st]; s1[tid] += s1[tid + st]; }
    __syncthreads();
  }
  float inv_n = 1.0f / (float)(NELEM_PER_B);
  float mu = s0[0] * inv_n;
  float var = s1[0] * inv_n - mu * mu;
  float rs = rsqrtf(var + 1e-5f);
  if (tid < NCH) {
    float A = rs * nw[tid];
    AC[b * 2 * NCH + tid] = A;
    AC[b * 2 * NCH + NCH + tid] = nb[tid] - mu * A;
  }
}

// Elementwise in-place: v = gelu(v*A[c] + C[c])  (norm1 affine + exact GELU)
__global__ void ew_norm_gelu(unsigned short* __restrict__ buf,
                             const float* __restrict__ AC) {
  size_t idx = ((size_t)blockIdx.x * 256 + threadIdx.x) * 8;
  int b = (int)(idx / NELEM_PER_B);
  int c0 = (int)(idx % NCH);  // 8-aligned (192 % 8 == 0)
  const float* A = AC + b * 2 * NCH;
  const float* C = A + NCH;
  s16x8 v = *(s16x8*)(buf + idx);
#pragma unroll
  for (int j = 0; j < 8; ++j) {
    float f = bf2f((unsigned short)v[j]);
    f = fmaf(f, A[c0 + j], C[c0 + j]);
    f = gelu_exact(f);
    v[j] = (short)f2bf(f);
  }
  *(s16x8*)(buf + idx) = v;
}

// fp32 -> bf16 weight conversion: slots 0=w1, 1=w22, 2=w21, 3=w23
__global__ void prep_weights(const float* __restrict__ w1, const float* __restrict__ w21,
                             const float* __restrict__ w22, const float* __restrict__ w23,
                             unsigned short* __restrict__ wb) {
  int i = blockIdx.x * 256 + threadIdx.x;
  if (i >= 4 * NCH * NCH) return;
  int m = i / (NCH * NCH), r = i % (NCH * NCH);
  const float* src = (m == 0) ? w1 : (m == 1) ? w22 : (m == 2) ? w21 : w23;
  wb[i] = f2bf(src[r]);
}

// Fold norm2 affine into w3/b3 per sample: w3e[b][o][c]=w3[o][c]*A2[b][c],
// b3e[b][o]=b3[o]+sum_c w3[o][c]*C2[b][c]
__global__ void prep_w3(const float* __restrict__ w3, const float* __restrict__ b3,
                        const float* __restrict__ AC2,
                        unsigned short* __restrict__ w3e, float* __restrict__ b3e) {
  int b = blockIdx.x;
  int o = threadIdx.x;
  if (o >= NCH) return;
  const float* A = AC2 + b * 2 * NCH;
  const float* C = A + NCH;
  float s = b3[o];
  for (int c = 0; c < NCH; ++c) {
    float w = w3[o * NCH + c];
    w3e[((size_t)b * NCH + o) * NCH + c] = f2bf(w * A[c]);
    s = fmaf(w, C[c], s);
  }
  b3e[b * NCH + o] = s;
}

extern "C" void kernel_launch(void* const* d_in, const int* in_sizes, int n_in,
                              void* d_out, int out_size, void* d_ws, size_t ws_size,
                              hipStream_t stream) {
  const float* x   = (const float*)d_in[0];
  const float* w1  = (const float*)d_in[1];
  const float* b1  = (const float*)d_in[2];
  const float* n1w = (const float*)d_in[3];
  const float* n1b = (const float*)d_in[4];
  const float* w21 = (const float*)d_in[5];
  const float* b21 = (const float*)d_in[6];
  const float* w22 = (const float*)d_in[7];
  const float* b22 = (const float*)d_in[8];
  const float* w23 = (const float*)d_in[9];
  const float* b23 = (const float*)d_in[10];
  const float* n2w = (const float*)d_in[11];
  const float* n2b = (const float*)d_in[12];
  const float* w3  = (const float*)d_in[13];
  const float* b3  = (const float*)d_in[14];

  char* ws = (char*)d_ws;
  size_t off = 0;
  unsigned short* wb = (unsigned short*)(ws + off); off += (size_t)4 * NCH * NCH * 2;
  off = (off + 255) & ~(size_t)255;
  unsigned short* w3e = (unsigned short*)(ws + off); off += (size_t)NB * NCH * NCH * 2;
  off = (off + 255) & ~(size_t)255;
  float* b3e = (float*)(ws + off); off += NB * NCH * 4;
  float* AC1 = (float*)(ws + off); off += NB * 2 * NCH * 4;
  float* AC2 = (float*)(ws + off); off += NB * 2 * NCH * 4;
  float* part1 = (float*)(ws + off); off += NWG * 2 * 4;
  float* part2 = (float*)(ws + off); off += NWG * 2 * 4;
  off = (off + 255) & ~(size_t)255;
  unsigned short* R1 = (unsigned short*)(ws + off);            // 100.7 MB in ws
  unsigned short* R2 = (unsigned short*)d_out;                 // bf16 scratch in d_out space

  prep_weights<<<(4 * NCH * NCH + 255) / 256, 256, 0, stream>>>(w1, w21, w22, w23, wb);

  // K1: x (f32 cmajor) -> R2, W=w1, stats1
  gemm_pass<0, 1, 0, 1, 0><<<NWG, 256, 0, stream>>>(x, wb + 0 * NCH * NCH, b1, R2, part1);
  stats_finalize<<<NB, 256, 0, stream>>>(part1, n1w, n1b, AC1);
  // E1: in-place norm1 affine + gelu on R2
  ew_norm_gelu<<<(int)(NB * NELEM_PER_B / 8 / 256), 256, 0, stream>>>(R2, AC1);
  // K2a: shift H(3), W=w22: R2 -> R1
  gemm_pass<3, 0, 0, 0, 0><<<NWG, 256, 0, stream>>>(R2, wb + 1 * NCH * NCH, b22, R1, nullptr);
  // K2b: shift D(2), W=w21: R1 -> R2
  gemm_pass<2, 0, 0, 0, 0><<<NWG, 256, 0, stream>>>(R1, wb + 2 * NCH * NCH, b21, R2, nullptr);
  // K2c: shift W(4), W=w23, epi gelu+stats2: R2 -> R1
  gemm_pass<4, 2, 0, 0, 0><<<NWG, 256, 0, stream>>>(R2, wb + 3 * NCH * NCH, b23, R1, part2);
  stats_finalize<<<NB, 256, 0, stream>>>(part2, n2w, n2b, AC2);
  prep_w3<<<NB, NCH, 0, stream>>>(w3, b3, AC2, w3e, b3e);
  // K3: folded norm2 + conv3, f32 channel-major out: R1 -> d_out
  gemm_pass<0, 0, 1, 0, 1><<<NWG, 256, 0, stream>>>(R1, w3e, b3e, d_out, part2);
}

// Round 2
// 414.995 us; speedup vs baseline: 1.4055x; 1.4055x over previous
//
#include <hip/hip_runtime.h>
#include <math.h>

#define NCH 192
#define NB 8
#define SPAT 32768           // 32^3
#define TILE_M 64
#define TILES_PER_B (SPAT / TILE_M)   // 512
#define NWG (NB * TILES_PER_B)        // 4096
#define NELEM_PER_B ((size_t)NCH * SPAT)  // 6291456

typedef short s16x8 __attribute__((ext_vector_type(8)));
typedef float f32x4 __attribute__((ext_vector_type(4)));

__device__ __forceinline__ float bf2f(unsigned short h) {
  return __uint_as_float(((unsigned)h) << 16);
}
__device__ __forceinline__ unsigned short f2bf(float f) {
  unsigned u = __float_as_uint(f);
  u += 0x7FFF + ((u >> 16) & 1);   // round-to-nearest-even
  return (unsigned short)(u >> 16);
}

// erf via Abramowitz-Stegun 7.1.26, |abs err| < 1.5e-7 (plenty vs 9e-2 budget)
__device__ __forceinline__ float erf_fast(float x) {
  float ax = fabsf(x);
  float t = 1.0f / fmaf(0.3275911f, ax, 1.0f);
  float p = t * fmaf(t, fmaf(t, fmaf(t, fmaf(t, 1.061405429f, -1.453152027f),
                                     1.421413741f), -0.284496736f), 0.254829592f);
  float r = 1.0f - p * __expf(-ax * ax);
  return copysignf(r, x);
}
__device__ __forceinline__ float gelu_exact(float x) {
  return 0.5f * x * (1.0f + erf_fast(x * 0.70710678118654752f));
}

// reflect-shift source position: out[i] = x[i-s], reflect(-1)->1, reflect(32)->30
template <int AX>  // 0 none, 2=D, 3=H, 4=W
__device__ __forceinline__ int shift_src(int p, int s) {
  if (AX == 0) return p;
  const int SH = (AX == 4) ? 0 : (AX == 3) ? 5 : 10;
  int i = (p >> SH) & 31;
  int j = i - s;
  j = (j < 0) ? 1 : j;
  j = (j > 31) ? 30 : j;
  return p + ((j - i) << SH);
}

// LDS tile layout: [chunk c:3][pos p:64][within-chunk ch u:64] bf16, with XOR
// swizzle byte ^= ((p&7)<<4) so stride-128B column reads spread across banks.
// SAME helper used by staging writes and fragment reads (both-sides rule).
__device__ __forceinline__ char* lds_addr(char* lds, int c, int p, int u) {
  return lds + ((c * 64 + p) * 128) + ((2 * u) ^ ((p & 7) << 4));
}

// ---------------------------------------------------------------------------
// GEMM pass with LDS-staged activation tile.
//   AX:   shift axis applied while gathering the tile (0 none, 2=D,3=H,4=W)
//   EPI:  0 bias only; 1 bias+stats; 2 bias+gelu+stats
//   OUTF: 0 bf16 position-major; 1 f32 channel-major (final output)
//   INF:  0 bf16 position-major; 1 f32 channel-major transpose-gather (K1)
//   PERB: per-sample weight/bias (folded norm2 in K3)
//   FUSE: apply y = gelu(y*A[ch]+C[ch]) per element during staging (norm1+gelu)
// Wave w computes out-channels [48w,48w+48) x 64 positions: 3x4 MFMA frags.
// ---------------------------------------------------------------------------
template <int AX, int EPI, int OUTF, int INF, int PERB, int FUSE>
__global__ __launch_bounds__(256, 4)
void gemm_pass(const void* __restrict__ inv,
               const unsigned short* __restrict__ wmat,
               const float* __restrict__ bias,
               void* __restrict__ outv,
               float* __restrict__ partials,
               const float* __restrict__ AC) {
  __shared__ char lds[3 * 64 * 128];   // 24 KB bf16 tile
  __shared__ float red[4][2];

  int wg = blockIdx.x;
  int b = wg / TILES_PER_B;
  int p0 = (wg % TILES_PER_B) * TILE_M;
  int tid = threadIdx.x;
  int wave = tid >> 6;
  int lane = tid & 63;
  int col = lane & 15;
  int kg = lane >> 4;

  const unsigned short* wbase = wmat + (PERB ? (size_t)b * NCH * NCH : 0);
  const float* bbase = bias + (PERB ? b * NCH : 0);
  const unsigned short* inb = (const unsigned short*)inv;
  const float* xin = (const float*)inv;

  // ---- Stage activation tile into LDS (gather handles the axial shift) ----
  {
    int c3 = tid >> 6;   // chunk 0..2 (wave 3 idle during staging)
    int p = tid & 63;
    if (c3 < 3) {
      const float* Af = FUSE ? (AC + b * 2 * NCH) : nullptr;
      const float* Cf = FUSE ? (Af + NCH) : nullptr;
      if (INF == 1) {
        // x fp32 channel-major: transpose-gather (coalesced 256B per channel)
        const float* src = xin + (size_t)b * NELEM_PER_B +
                           (size_t)(c3 * 64) * SPAT + (p0 + p);
#pragma unroll
        for (int j = 0; j < 8; ++j) {
          s16x8 v;
#pragma unroll
          for (int u = 0; u < 8; ++u)
            v[u] = (short)f2bf(src[(size_t)(8 * j + u) * SPAT]);
          *(s16x8*)lds_addr(lds, c3, p, 8 * j) = v;
        }
      } else {
        int s_ = c3 - 1;   // channel-chunk shift: -1, 0, +1
        int ps = shift_src<AX>(p0 + p, s_);
        const unsigned short* src = inb + ((size_t)b * SPAT + ps) * NCH + c3 * 64;
#pragma unroll
        for (int j = 0; j < 8; ++j) {
          s16x8 v = *(const s16x8*)(src + 8 * j);
          if (FUSE) {
#pragma unroll
            for (int u = 0; u < 8; ++u) {
              int ch = c3 * 64 + 8 * j + u;
              float f = bf2f((unsigned short)v[u]);
              f = fmaf(f, Af[ch], Cf[ch]);
              f = gelu_exact(f);
              v[u] = (short)f2bf(f);
            }
          }
          *(s16x8*)lds_addr(lds, c3, p, 8 * j) = v;
        }
      }
    }
  }
  __syncthreads();

  // ---- MFMA main loop: A from global (L1/L2-resident weights), B from LDS ----
  f32x4 acc[3][4] = {};
#pragma unroll
  for (int ks = 0; ks < 6; ++ks) {
    int k0 = ks * 32 + kg * 8;
    s16x8 af[3];
#pragma unroll
    for (int r = 0; r < 3; ++r) {
      int row = wave * 48 + r * 16 + col;
      af[r] = *(const s16x8*)(wbase + row * NCH + k0);
    }
    int c = k0 >> 6, u = k0 & 63;
    s16x8 bf[4];
#pragma unroll
    for (int m = 0; m < 4; ++m)
      bf[m] = *(const s16x8*)lds_addr(lds, c, m * 16 + col, u);
#pragma unroll
    for (int r = 0; r < 3; ++r)
#pragma unroll
      for (int m = 0; m < 4; ++m)
        acc[r][m] = __builtin_amdgcn_mfma_f32_16x16x32_bf16(af[r], bf[m], acc[r][m], 0, 0, 0);
  }

  // ---- Epilogue: D mapping col=lane&15, row=(lane>>4)*4+j [m89-verified] ----
  float ssum = 0.f, ssq = 0.f;
  unsigned short* outb = (unsigned short*)outv;
  float* outf = (float*)outv;
#pragma unroll
  for (int r = 0; r < 3; ++r) {
    int rowb = wave * 48 + r * 16 + kg * 4;
    f32x4 bs = *(const f32x4*)(bbase + rowb);
#pragma unroll
    for (int m = 0; m < 4; ++m) {
      int p = p0 + m * 16 + col;
      float v[4];
#pragma unroll
      for (int j = 0; j < 4; ++j) {
        float t = acc[r][m][j] + bs[j];
        if (EPI == 2) t = gelu_exact(t);
        if (EPI >= 1) { ssum += t; ssq = fmaf(t, t, ssq); }
        v[j] = t;
      }
      if (OUTF == 0) {
        uint2 pk;
        pk.x = (unsigned)f2bf(v[0]) | ((unsigned)f2bf(v[1]) << 16);
        pk.y = (unsigned)f2bf(v[2]) | ((unsigned)f2bf(v[3]) << 16);
        *(uint2*)(outb + ((size_t)b * SPAT + p) * NCH + rowb) = pk;
      } else {
#pragma unroll
        for (int j = 0; j < 4; ++j)
          outf[((size_t)b * NCH + rowb + j) * SPAT + p] = v[j];
      }
    }
  }

  if (EPI >= 1) {
#pragma unroll
    for (int off = 1; off < 64; off <<= 1) {
      ssum += __shfl_xor(ssum, off, 64);
      ssq += __shfl_xor(ssq, off, 64);
    }
    if (lane == 0) { red[wave][0] = ssum; red[wave][1] = ssq; }
    __syncthreads();
    if (tid == 0) {
      partials[wg * 2]     = red[0][0] + red[1][0] + red[2][0] + red[3][0];
      partials[wg * 2 + 1] = red[0][1] + red[1][1] + red[2][1] + red[3][1];
    }
  }
}

// Deterministic per-sample stats finalize: partials -> A[c]=rs*nw[c], C[c]=nb[c]-mu*A[c]
__global__ void stats_finalize(const float* __restrict__ partials,
                               const float* __restrict__ nw,
                               const float* __restrict__ nb,
                               float* __restrict__ AC) {
  int b = blockIdx.x;
  int tid = threadIdx.x;
  __shared__ float s0[256], s1[256];
  float a = 0.f, c = 0.f;
  for (int i = tid; i < TILES_PER_B; i += 256) {
    a += partials[(b * TILES_PER_B + i) * 2];
    c += partials[(b * TILES_PER_B + i) * 2 + 1];
  }
  s0[tid] = a; s1[tid] = c;
  __syncthreads();
  for (int st = 128; st > 0; st >>= 1) {
    if (tid < st) { s0[tid] += s0[tid + st]; s1[tid] += s1[tid + st]; }
    __syncthreads();
  }
  float inv_n = 1.0f / (float)(NELEM_PER_B);
  float mu = s0[0] * inv_n;
  float var = s1[0] * inv_n - mu * mu;
  float rs = rsqrtf(var + 1e-5f);
  if (tid < NCH) {
    float A = rs * nw[tid];
    AC[b * 2 * NCH + tid] = A;
    AC[b * 2 * NCH + NCH + tid] = nb[tid] - mu * A;
  }
}

// fp32 -> bf16 weight conversion: slots 0=w1, 1=w22, 2=w21, 3=w23
__global__ void prep_weights(const float* __restrict__ w1, const float* __restrict__ w21,
                             const float* __restrict__ w22, const float* __restrict__ w23,
                             unsigned short* __restrict__ wb) {
  int i = blockIdx.x * 256 + threadIdx.x;
  if (i >= 4 * NCH * NCH) return;
  int m = i / (NCH * NCH), r = i % (NCH * NCH);
  const float* src = (m == 0) ? w1 : (m == 1) ? w22 : (m == 2) ? w21 : w23;
  wb[i] = f2bf(src[r]);
}

// Fold norm2 affine into w3/b3 per sample: w3e[b][o][c]=w3[o][c]*A2[b][c],
// b3e[b][o]=b3[o]+sum_c w3[o][c]*C2[b][c]
__global__ void prep_w3(const float* __restrict__ w3, const float* __restrict__ b3,
                        const float* __restrict__ AC2,
                        unsigned short* __restrict__ w3e, float* __restrict__ b3e) {
  int b = blockIdx.x;
  int o = threadIdx.x;
  if (o >= NCH) return;
  const float* A = AC2 + b * 2 * NCH;
  const float* C = A + NCH;
  float s = b3[o];
  for (int c = 0; c < NCH; ++c) {
    float w = w3[o * NCH + c];
    w3e[((size_t)b * NCH + o) * NCH + c] = f2bf(w * A[c]);
    s = fmaf(w, C[c], s);
  }
  b3e[b * NCH + o] = s;
}

extern "C" void kernel_launch(void* const* d_in, const int* in_sizes, int n_in,
                              void* d_out, int out_size, void* d_ws, size_t ws_size,
                              hipStream_t stream) {
  const float* x   = (const float*)d_in[0];
  const float* w1  = (const float*)d_in[1];
  const float* b1  = (const float*)d_in[2];
  const float* n1w = (const float*)d_in[3];
  const float* n1b = (const float*)d_in[4];
  const float* w21 = (const float*)d_in[5];
  const float* b21 = (const float*)d_in[6];
  const float* w22 = (const float*)d_in[7];
  const float* b22 = (const float*)d_in[8];
  const float* w23 = (const float*)d_in[9];
  const float* b23 = (const float*)d_in[10];
  const float* n2w = (const float*)d_in[11];
  const float* n2b = (const float*)d_in[12];
  const float* w3  = (const float*)d_in[13];
  const float* b3  = (const float*)d_in[14];

  char* ws = (char*)d_ws;
  size_t off = 0;
  unsigned short* wb = (unsigned short*)(ws + off); off += (size_t)4 * NCH * NCH * 2;
  off = (off + 255) & ~(size_t)255;
  unsigned short* w3e = (unsigned short*)(ws + off); off += (size_t)NB * NCH * NCH * 2;
  off = (off + 255) & ~(size_t)255;
  float* b3e = (float*)(ws + off); off += NB * NCH * 4;
  float* AC1 = (float*)(ws + off); off += NB * 2 * NCH * 4;
  float* AC2 = (float*)(ws + off); off += NB * 2 * NCH * 4;
  float* part1 = (float*)(ws + off); off += NWG * 2 * 4;
  float* part2 = (float*)(ws + off); off += NWG * 2 * 4;
  off = (off + 255) & ~(size_t)255;
  unsigned short* R1 = (unsigned short*)(ws + off);            // 100.7 MB in ws
  unsigned short* R2 = (unsigned short*)d_out;                 // bf16 scratch in d_out space

  prep_weights<<<(4 * NCH * NCH + 255) / 256, 256, 0, stream>>>(w1, w21, w22, w23, wb);

  // K1: x (f32 cmajor) -> R2 via LDS transpose, W=w1, stats1
  gemm_pass<0, 1, 0, 1, 0, 0><<<NWG, 256, 0, stream>>>(x, wb + 0 * NCH * NCH, b1, R2, part1, nullptr);
  stats_finalize<<<NB, 256, 0, stream>>>(part1, n1w, n1b, AC1);
  // K2a: fused norm1+gelu during staging, shift H(3), W=w22: R2 -> R1
  gemm_pass<3, 0, 0, 0, 0, 1><<<NWG, 256, 0, stream>>>(R2, wb + 1 * NCH * NCH, b22, R1, nullptr, AC1);
  // K2b: shift D(2), W=w21: R1 -> R2
  gemm_pass<2, 0, 0, 0, 0, 0><<<NWG, 256, 0, stream>>>(R1, wb + 2 * NCH * NCH, b21, R2, nullptr, nullptr);
  // K2c: shift W(4), W=w23, epi gelu+stats2: R2 -> R1
  gemm_pass<4, 2, 0, 0, 0, 0><<<NWG, 256, 0, stream>>>(R2, wb + 3 * NCH * NCH, b23, R1, part2, nullptr);
  stats_finalize<<<NB, 256, 0, stream>>>(part2, n2w, n2b, AC2);
  prep_w3<<<NB, NCH, 0, stream>>>(w3, b3, AC2, w3e, b3e);
  // K3: folded norm2 + conv3, f32 channel-major out: R1 -> d_out
  gemm_pass<0, 0, 1, 0, 1, 0><<<NWG, 256, 0, stream>>>(R1, w3e, b3e, d_out, part2, nullptr);
}

// Round 3
// 388.379 us; speedup vs baseline: 1.5019x; 1.0685x over previous
//
#include <hip/hip_runtime.h>
#include <math.h>

#define NCH 192
#define NB 8
#define SPAT 32768           // 32^3
#define TILE_M 64
#define TILES_PER_B (SPAT / TILE_M)   // 512
#define NWG (NB * TILES_PER_B)        // 4096
#define NELEM_PER_B ((size_t)NCH * SPAT)  // 6291456

typedef short s16x8 __attribute__((ext_vector_type(8)));
typedef float f32x4 __attribute__((ext_vector_type(4)));

__device__ __forceinline__ float bf2f(unsigned short h) {
  return __uint_as_float(((unsigned)h) << 16);
}
__device__ __forceinline__ unsigned short f2bf(float f) {
  unsigned u = __float_as_uint(f);
  u += 0x7FFF + ((u >> 16) & 1);   // round-to-nearest-even
  return (unsigned short)(u >> 16);
}

// erf via Abramowitz-Stegun 7.1.26, |abs err| < 1.5e-7 (plenty vs 9e-2 budget)
__device__ __forceinline__ float erf_fast(float x) {
  float ax = fabsf(x);
  float t = 1.0f / fmaf(0.3275911f, ax, 1.0f);
  float p = t * fmaf(t, fmaf(t, fmaf(t, fmaf(t, 1.061405429f, -1.453152027f),
                                     1.421413741f), -0.284496736f), 0.254829592f);
  float r = 1.0f - p * __expf(-ax * ax);
  return copysignf(r, x);
}
__device__ __forceinline__ float gelu_exact(float x) {
  return 0.5f * x * (1.0f + erf_fast(x * 0.70710678118654752f));
}

// reflect-shift source position: out[i] = x[i-s], reflect(-1)->1, reflect(32)->30
template <int AX>  // 0 none, 2=D, 3=H, 4=W
__device__ __forceinline__ int shift_src(int p, int s) {
  if (AX == 0) return p;
  const int SH = (AX == 4) ? 0 : (AX == 3) ? 5 : 10;
  int i = (p >> SH) & 31;
  int j = i - s;
  j = (j < 0) ? 1 : j;
  j = (j > 31) ? 30 : j;
  return p + ((j - i) << SH);
}

// LDS tile layout: [chunk c:3][pos p:64][within-chunk ch u:64] bf16, with XOR
// swizzle byte ^= ((p&7)<<4). SAME formula on every write and read.
__device__ __forceinline__ int lds_off(int c, int p, int inner_byte) {
  return (c * 64 + p) * 128 + (inner_byte ^ ((p & 7) << 4));
}

// ---------------------------------------------------------------------------
// GEMM pass, fully coalesced global I/O via LDS round-trips.
//   AX:   shift axis applied while gathering the tile (0 none, 2=D,3=H,4=W)
//   EPI:  0 bias only; 1 bias+stats; 2 bias+gelu+stats
//   OUTF: 0 bf16 position-major (LDS-staged coalesced store); 1 f32 ch-major
//   INF:  0 bf16 position-major (coalesced chunk gather); 1 f32 ch-major (K1)
//   PERB: per-sample weight/bias (folded norm2 in K3)
//   FUSE: y = gelu(y*A[ch]+C[ch]) in-register during staging (norm1+gelu)
// Wave w computes out-channels [48w,48w+48) x 64 positions: 3x4 MFMA frags.
// ---------------------------------------------------------------------------
template <int AX, int EPI, int OUTF, int INF, int PERB, int FUSE>
__global__ __launch_bounds__(256, 4)
void gemm_pass(const void* __restrict__ inv,
               const unsigned short* __restrict__ wmat,
               const float* __restrict__ bias,
               void* __restrict__ outv,
               float* __restrict__ partials,
               const float* __restrict__ AC) {
  __shared__ __align__(16) char lds[3 * 64 * 128];   // 24 KB bf16 tile
  __shared__ float acs[2 * NCH];                     // FUSE affine cache
  __shared__ float red[4][2];

  int wg = blockIdx.x;
  int b = wg / TILES_PER_B;
  int p0 = (wg % TILES_PER_B) * TILE_M;
  int tid = threadIdx.x;
  int wave = tid >> 6;
  int lane = tid & 63;
  int col = lane & 15;
  int kg = lane >> 4;

  const unsigned short* wbase = wmat + (PERB ? (size_t)b * NCH * NCH : 0);
  const float* bbase = bias + (PERB ? b * NCH : 0);
  const char* inbytes = (const char*)inv;
  const float* xin = (const float*)inv;

  if (FUSE) {
    for (int i = tid; i < 2 * NCH; i += 256) acs[i] = AC[b * 2 * NCH + i];
    __syncthreads();
  }

  // ---- Stage activation tile into LDS (coalesced; gather handles shift) ----
  if (INF == 1) {
    // x fp32 channel-major: transpose-gather (256B coalesced per instruction)
    int c3 = tid >> 6;   // chunk 0..2 (wave 3 idle during staging)
    int p = tid & 63;
    if (c3 < 3) {
      const float* src = xin + (size_t)b * NELEM_PER_B +
                         (size_t)(c3 * 64) * SPAT + (p0 + p);
#pragma unroll
      for (int j = 0; j < 8; ++j) {
        s16x8 v;
#pragma unroll
        for (int u = 0; u < 8; ++u)
          v[u] = (short)f2bf(src[(size_t)(8 * j + u) * SPAT]);
        *(s16x8*)(lds + lds_off(c3, p, j * 16)) = v;
      }
    }
  } else {
    // bf16 [p][c]: tile rows are 384B contiguous; chunk-indexed cooperative
    // gather -> lanes form contiguous 384B runs (fully-used cache lines).
#pragma unroll
    for (int j = 0; j < 6; ++j) {
      unsigned g = j * 256 + tid;          // 16B chunk id, 0..1535
      int p = (int)(g / 24u);
      int r24 = (int)(g - 24u * (unsigned)p);
      int c = r24 >> 3;
      int ps = shift_src<AX>(p0 + p, c - 1);
      s16x8 v = *(const s16x8*)(inbytes + ((size_t)b * SPAT + ps) * 384 + r24 * 16);
      if (FUSE) {
        int ch0 = r24 * 8;
#pragma unroll
        for (int u = 0; u < 8; ++u) {
          float f = bf2f((unsigned short)v[u]);
          f = fmaf(f, acs[ch0 + u], acs[NCH + ch0 + u]);
          f = gelu_exact(f);
          v[u] = (short)f2bf(f);
        }
      }
      *(s16x8*)(lds + lds_off(c, p, (r24 & 7) * 16)) = v;
    }
  }
  __syncthreads();

  // ---- MFMA main loop: A from global (L2-resident weights), B from LDS ----
  f32x4 acc[3][4] = {};
#pragma unroll
  for (int ks = 0; ks < 6; ++ks) {
    int k0 = ks * 32 + kg * 8;
    s16x8 af[3];
#pragma unroll
    for (int r = 0; r < 3; ++r) {
      int row = wave * 48 + r * 16 + col;
      af[r] = *(const s16x8*)(wbase + row * NCH + k0);
    }
    int c = k0 >> 6, u = k0 & 63;
    s16x8 bf[4];
#pragma unroll
    for (int m = 0; m < 4; ++m)
      bf[m] = *(const s16x8*)(lds + lds_off(c, m * 16 + col, 2 * u));
#pragma unroll
    for (int r = 0; r < 3; ++r)
#pragma unroll
      for (int m = 0; m < 4; ++m)
        acc[r][m] = __builtin_amdgcn_mfma_f32_16x16x32_bf16(af[r], bf[m], acc[r][m], 0, 0, 0);
  }

  // ---- Epilogue: D mapping col=lane&15, row=(lane>>4)*4+j [m89-verified] ----
  float ssum = 0.f, ssq = 0.f;
  float* outf = (float*)outv;
  if (OUTF == 0) __syncthreads();   // all B-frag reads done; LDS tile is dead
#pragma unroll
  for (int r = 0; r < 3; ++r) {
    int rowb = wave * 48 + r * 16 + kg * 4;
    f32x4 bs = *(const f32x4*)(bbase + rowb);
#pragma unroll
    for (int m = 0; m < 4; ++m) {
      int p = m * 16 + col;
      float v[4];
#pragma unroll
      for (int j = 0; j < 4; ++j) {
        float t = acc[r][m][j] + bs[j];
        if (EPI == 2) t = gelu_exact(t);
        if (EPI >= 1) { ssum += t; ssq = fmaf(t, t, ssq); }
        v[j] = t;
      }
      if (OUTF == 0) {
        // pack 4 consecutive out-channels (8B) into the LDS tile
        uint2 pk;
        pk.x = (unsigned)f2bf(v[0]) | ((unsigned)f2bf(v[1]) << 16);
        pk.y = (unsigned)f2bf(v[2]) | ((unsigned)f2bf(v[3]) << 16);
        *(uint2*)(lds + lds_off(rowb >> 6, p, 2 * (rowb & 63))) = pk;
      } else {
#pragma unroll
        for (int j = 0; j < 4; ++j)
          outf[((size_t)b * NCH + rowb + j) * SPAT + p0 + p] = v[j];
      }
    }
  }

  if (OUTF == 0) {
    __syncthreads();
    // cooperative coalesced store: tile is contiguous 24KB in global
    char* outbytes = (char*)outv + ((size_t)b * SPAT + p0) * 384;
#pragma unroll
    for (int j = 0; j < 6; ++j) {
      unsigned g = j * 256 + tid;
      int p = (int)(g / 24u);
      int r24 = (int)(g - 24u * (unsigned)p);
      int c = r24 >> 3;
      s16x8 v = *(const s16x8*)(lds + lds_off(c, p, (r24 & 7) * 16));
      *(s16x8*)(outbytes + g * 16) = v;
    }
  }

  if (EPI >= 1) {
#pragma unroll
    for (int off = 1; off < 64; off <<= 1) {
      ssum += __shfl_xor(ssum, off, 64);
      ssq += __shfl_xor(ssq, off, 64);
    }
    if (lane == 0) { red[wave][0] = ssum; red[wave][1] = ssq; }
    __syncthreads();
    if (tid == 0) {
      partials[wg * 2]     = red[0][0] + red[1][0] + red[2][0] + red[3][0];
      partials[wg * 2 + 1] = red[0][1] + red[1][1] + red[2][1] + red[3][1];
    }
  }
}

// Deterministic per-sample stats finalize: partials -> A[c]=rs*nw[c], C[c]=nb[c]-mu*A[c]
__global__ void stats_finalize(const float* __restrict__ partials,
                               const float* __restrict__ nw,
                               const float* __restrict__ nb,
                               float* __restrict__ AC) {
  int b = blockIdx.x;
  int tid = threadIdx.x;
  __shared__ float s0[256], s1[256];
  float a = 0.f, c = 0.f;
  for (int i = tid; i < TILES_PER_B; i += 256) {
    a += partials[(b * TILES_PER_B + i) * 2];
    c += partials[(b * TILES_PER_B + i) * 2 + 1];
  }
  s0[tid] = a; s1[tid] = c;
  __syncthreads();
  for (int st = 128; st > 0; st >>= 1) {
    if (tid < st) { s0[tid] += s0[tid + st]; s1[tid] += s1[tid + st]; }
    __syncthreads();
  }
  float inv_n = 1.0f / (float)(NELEM_PER_B);
  float mu = s0[0] * inv_n;
  float var = s1[0] * inv_n - mu * mu;
  float rs = rsqrtf(var + 1e-5f);
  if (tid < NCH) {
    float A = rs * nw[tid];
    AC[b * 2 * NCH + tid] = A;
    AC[b * 2 * NCH + NCH + tid] = nb[tid] - mu * A;
  }
}

// fp32 -> bf16 weight conversion: slots 0=w1, 1=w22, 2=w21, 3=w23
__global__ void prep_weights(const float* __restrict__ w1, const float* __restrict__ w21,
                             const float* __restrict__ w22, const float* __restrict__ w23,
                             unsigned short* __restrict__ wb) {
  int i = blockIdx.x * 256 + threadIdx.x;
  if (i >= 4 * NCH * NCH) return;
  int m = i / (NCH * NCH), r = i % (NCH * NCH);
  const float* src = (m == 0) ? w1 : (m == 1) ? w22 : (m == 2) ? w21 : w23;
  wb[i] = f2bf(src[r]);
}

// Fold norm2 affine into w3/b3 per sample: w3e[b][o][c]=w3[o][c]*A2[b][c],
// b3e[b][o]=b3[o]+sum_c w3[o][c]*C2[b][c]
__global__ void prep_w3(const float* __restrict__ w3, const float* __restrict__ b3,
                        const float* __restrict__ AC2,
                        unsigned short* __restrict__ w3e, float* __restrict__ b3e) {
  int b = blockIdx.x;
  int o = threadIdx.x;
  if (o >= NCH) return;
  const float* A = AC2 + b * 2 * NCH;
  const float* C = A + NCH;
  float s = b3[o];
  for (int c = 0; c < NCH; ++c) {
    float w = w3[o * NCH + c];
    w3e[((size_t)b * NCH + o) * NCH + c] = f2bf(w * A[c]);
    s = fmaf(w, C[c], s);
  }
  b3e[b * NCH + o] = s;
}

extern "C" void kernel_launch(void* const* d_in, const int* in_sizes, int n_in,
                              void* d_out, int out_size, void* d_ws, size_t ws_size,
                              hipStream_t stream) {
  const float* x   = (const float*)d_in[0];
  const float* w1  = (const float*)d_in[1];
  const float* b1  = (const float*)d_in[2];
  const float* n1w = (const float*)d_in[3];
  const float* n1b = (const float*)d_in[4];
  const float* w21 = (const float*)d_in[5];
  const float* b21 = (const float*)d_in[6];
  const float* w22 = (const float*)d_in[7];
  const float* b22 = (const float*)d_in[8];
  const float* w23 = (const float*)d_in[9];
  const float* b23 = (const float*)d_in[10];
  const float* n2w = (const float*)d_in[11];
  const float* n2b = (const float*)d_in[12];
  const float* w3  = (const float*)d_in[13];
  const float* b3  = (const float*)d_in[14];

  char* ws = (char*)d_ws;
  size_t off = 0;
  unsigned short* wb = (unsigned short*)(ws + off); off += (size_t)4 * NCH * NCH * 2;
  off = (off + 255) & ~(size_t)255;
  unsigned short* w3e = (unsigned short*)(ws + off); off += (size_t)NB * NCH * NCH * 2;
  off = (off + 255) & ~(size_t)255;
  float* b3e = (float*)(ws + off); off += NB * NCH * 4;
  float* AC1 = (float*)(ws + off); off += NB * 2 * NCH * 4;
  float* AC2 = (float*)(ws + off); off += NB * 2 * NCH * 4;
  float* part1 = (float*)(ws + off); off += NWG * 2 * 4;
  float* part2 = (float*)(ws + off); off += NWG * 2 * 4;
  off = (off + 255) & ~(size_t)255;
  unsigned short* R1 = (unsigned short*)(ws + off);            // 100.7 MB in ws
  unsigned short* R2 = (unsigned short*)d_out;                 // bf16 scratch in d_out space

  prep_weights<<<(4 * NCH * NCH + 255) / 256, 256, 0, stream>>>(w1, w21, w22, w23, wb);

  // K1: x (f32 cmajor) -> R2 via LDS transpose, W=w1, stats1
  gemm_pass<0, 1, 0, 1, 0, 0><<<NWG, 256, 0, stream>>>(x, wb + 0 * NCH * NCH, b1, R2, part1, nullptr);
  stats_finalize<<<NB, 256, 0, stream>>>(part1, n1w, n1b, AC1);
  // K2a: fused norm1+gelu during staging, shift H(3), W=w22: R2 -> R1
  gemm_pass<3, 0, 0, 0, 0, 1><<<NWG, 256, 0, stream>>>(R2, wb + 1 * NCH * NCH, b22, R1, nullptr, AC1);
  // K2b: shift D(2), W=w21: R1 -> R2
  gemm_pass<2, 0, 0, 0, 0, 0><<<NWG, 256, 0, stream>>>(R1, wb + 2 * NCH * NCH, b21, R2, nullptr, nullptr);
  // K2c: shift W(4), W=w23, epi gelu+stats2: R2 -> R1
  gemm_pass<4, 2, 0, 0, 0, 0><<<NWG, 256, 0, stream>>>(R2, wb + 3 * NCH * NCH, b23, R1, part2, nullptr);
  stats_finalize<<<NB, 256, 0, stream>>>(part2, n2w, n2b, AC2);
  prep_w3<<<NB, NCH, 0, stream>>>(w3, b3, AC2, w3e, b3e);
  // K3: folded norm2 + conv3, f32 channel-major out: R1 -> d_out
  gemm_pass<0, 0, 1, 0, 1, 0><<<NWG, 256, 0, stream>>>(R1, w3e, b3e, d_out, part2, nullptr);
}